// Round 4
// baseline (133.277 us; speedup 1.0000x reference)
//
#include <hip/hip_runtime.h>
#include <cstdint>
#include <cstddef>

// Problem constants
#define B_DIM 4096   // batch (GEMM M)
#define S_DIM 2048   // states (GEMM N)
#define D_DIM 2496   // feature dim (GEMM K)
#define QSCALE 127.0f
#define QSCALE2 16129.0f   // 127^2

// R10: R7/R8/R9 falsified drain, bank-conflict, and L2-drift theories (all
// landed 127.7-128.7). Remaining largest gemm term by pipe arithmetic: LDS
// port occupancy (reads 12.5us + staging writes 4.2us per CU > MFMA 10.6us).
// Fix: B fragments bypass LDS entirely — slot-major layout makes a B frag a
// contiguous coalesced global_load_dwordx4; B panel is L2-resident under the
// R9 XCD mapping and L1-dedupes across the wm-wave pair. B rides the counted
// pipeline at depth 2 via three static register sets. LDS now serves A only:
// pipe drops to ~8.4us < MFMA 10.6us. A staging/3-buffer/vmcnt scheme and
// the verified epilogue are byte-identical to R9.
#define BM 128
#define BN 128
#define BK 64
#define KITERS (D_DIM / BK)   // 39 k-chunks of 64 bytes
#define ABUF (BM * BK)        // 8192 B per A buffer

typedef __attribute__((ext_vector_type(4))) int int4v;

// ---------------------------------------------------------------------------
struct __attribute__((aligned(8))) uc8 { unsigned char c[8]; };

// Prep, wave-per-row: quantize one row to u8 in [0,127] (RTN), EXACT fp32
// squared norm via shuffle reduce. Output layout (per array): chunks of
// 16 rows x 64 k-bytes, chunkbase = (rowblock*39 + kchunk)*1024, and WITHIN
// a chunk slot-major: offset = ((k>>4)&3)*256 + (row&15)*16 + (k&15).
// A linear 1024-B copy of a chunk (base + lane*16) IS the i8 16x16x64
// fragment (m=lane&15, k16slot=lane>>4) — used by LDS (A) and direct (B).
__global__ __launch_bounds__(256) void prep_kernel(
    const float* __restrict__ X, const float* __restrict__ Mx,
    unsigned char* __restrict__ Xq, unsigned char* __restrict__ Mq,
    float* __restrict__ xsq, float* __restrict__ msq)
{
    const int lane = threadIdx.x & 63;
    const int row  = blockIdx.x * 4 + (threadIdx.x >> 6);

    const float* src; unsigned char* dstbase; float* sq;
    if (row < B_DIM) {
        src = X + (size_t)row * D_DIM;
        dstbase = Xq + (size_t)(row >> 4) * (KITERS * 1024) + (row & 15) * 16;
        sq = xsq + row;
    } else {
        const int r = row - B_DIM;
        src = Mx + (size_t)r * D_DIM;
        dstbase = Mq + (size_t)(r >> 4) * (KITERS * 1024) + (r & 15) * 16;
        sq = msq + r;
    }

    const float4* s4 = (const float4*)src;
    float acc = 0.f;
    for (int i = lane; i < D_DIM / 8; i += 64) {   // i indexes 8-byte k-groups
        float4 a = s4[2 * i], b = s4[2 * i + 1];
        acc += a.x * a.x + a.y * a.y + a.z * a.z + a.w * a.w;
        acc += b.x * b.x + b.y * b.y + b.z * b.z + b.w * b.w;
        uc8 q;
        q.c[0] = (unsigned char)__float2int_rn(a.x * QSCALE);
        q.c[1] = (unsigned char)__float2int_rn(a.y * QSCALE);
        q.c[2] = (unsigned char)__float2int_rn(a.z * QSCALE);
        q.c[3] = (unsigned char)__float2int_rn(a.w * QSCALE);
        q.c[4] = (unsigned char)__float2int_rn(b.x * QSCALE);
        q.c[5] = (unsigned char)__float2int_rn(b.y * QSCALE);
        q.c[6] = (unsigned char)__float2int_rn(b.z * QSCALE);
        q.c[7] = (unsigned char)__float2int_rn(b.w * QSCALE);
        // k = i*8: kchunk = i>>3, slot = (i>>1)&3, byte-in-slot = (i&1)*8
        *(uc8*)(dstbase + (i >> 3) * 1024 + ((i >> 1) & 3) * 256 + (i & 1) * 8) = q;
    }
    #pragma unroll
    for (int off = 32; off > 0; off >>= 1)
        acc += __shfl_down(acc, off, 64);
    if (lane == 0) *sq = acc;
}

// ---------------------------------------------------------------------------
// global -> LDS direct (async) load, 16 B per lane.
__device__ __forceinline__ void gld_lds16(const unsigned char* g, unsigned char* l) {
    __builtin_amdgcn_global_load_lds(
        (const __attribute__((address_space(1))) unsigned int*)g,
        (__attribute__((address_space(3))) unsigned int*)l,
        16, 0, 0);
}

// ---------------------------------------------------------------------------
__global__ __launch_bounds__(256) void gemm_kernel(
    const unsigned char* __restrict__ A,   // slot-major chunked [256 rb][39 kc][1024]
    const unsigned char* __restrict__ Bt,  // slot-major chunked [128 rb][39 kc][1024]
    const float* __restrict__ xsq, const float* __restrict__ msq,
    float* __restrict__ C)
{
    constexpr int N = S_DIM;

    __shared__ __align__(16) unsigned char lds[3 * ABUF];  // 24 KB, A only

    const int tid  = threadIdx.x;
    const int lane = tid & 63;
    const int wave = tid >> 6;       // 4 waves, 2x2 of 64x64
    const int wm = wave >> 1;
    const int wn = wave & 1;

    // B-panel-resident XCD mapping (R9): xcd = bid&7 round-robin (m09).
    //   bn = 2*xcd + (l&1)  -> B panel 0.64 MB, L2-resident all kernel.
    //   bm = l>>1           -> A-chunk shared by the adjacent l-pair only.
    const int bid = blockIdx.x;
    const int xcd = bid & 7;
    const int l   = bid >> 3;              // 0..63 within XCD
    const int bm  = l >> 1;                // 0..31
    const int bn  = xcd * 2 + (l & 1);     // 0..15

    // A staging: per K-step each wave copies 2 chunks (rowblocks 2w, 2w+1),
    // each a contiguous 1 KB at base + lane*16.
    const unsigned char* pA0 = A + (size_t)((bm * 8 + 2 * wave    ) * KITERS) * 1024 + lane * 16;
    const unsigned char* pA1 = A + (size_t)((bm * 8 + 2 * wave + 1) * KITERS) * 1024 + lane * 16;
    const int dA0 = (2 * wave) * 1024;
    const int dA1 = dA0 + 1024;

    // B fragment pointers (direct global->VGPR): this wave's wn-half,
    // rowblocks bn*8 + wn*4 + i. Each frag = coalesced 16 B/lane.
    const unsigned char* pB0 = Bt + (size_t)((bn * 8 + wn * 4 + 0) * KITERS) * 1024 + lane * 16;
    const unsigned char* pB1 = Bt + (size_t)((bn * 8 + wn * 4 + 1) * KITERS) * 1024 + lane * 16;
    const unsigned char* pB2 = Bt + (size_t)((bn * 8 + wn * 4 + 2) * KITERS) * 1024 + lane * 16;
    const unsigned char* pB3 = Bt + (size_t)((bn * 8 + wn * 4 + 3) * KITERS) * 1024 + lane * 16;

    int4v acc[4][4] = {};

    // A fragment read offsets: linear lane*16 within each chunk (conflict-free).
    const int aoff = wm * 4096 + lane * 16;

    // Three static B register sets (rule #20: no runtime indexing).
    int4v b0f[4], b1f[4], b2f[4];

// Load one tile's B frags into a named set; pointers advance one chunk.
#define LDB(SET) do { \
    SET[0] = *(const int4v*)pB0; SET[1] = *(const int4v*)pB1; \
    SET[2] = *(const int4v*)pB2; SET[3] = *(const int4v*)pB3; \
    pB0 += 1024; pB1 += 1024; pB2 += 1024; pB3 += 1024; \
} while (0)

#define AGLD(BUF) do { \
    gld_lds16(pA0, &lds[(BUF) + dA0]); \
    gld_lds16(pA1, &lds[(BUF) + dA1]); \
    pA0 += 1024; pA1 += 1024; \
} while (0)

#define COMPUTE(BUF, BSET) do { \
    int4v af[4]; \
    _Pragma("unroll") \
    for (int i = 0; i < 4; ++i) \
        af[i] = *(const int4v*)&lds[(BUF) + aoff + i * 1024]; \
    _Pragma("unroll") \
    for (int mi = 0; mi < 4; ++mi) \
        _Pragma("unroll") \
        for (int ni = 0; ni < 4; ++ni) \
            acc[mi][ni] = __builtin_amdgcn_mfma_i32_16x16x64_i8( \
                af[mi], BSET[ni], acc[mi][ni], 0, 0, 0); \
} while (0)

// Steady state: before step t's wait, outstanding = [B(t) 4, A(t) 2,
// B(t+1) 4, A(t+1) 2] (issue order LDB-then-AGLD per step). vmcnt(6)
// retires B(t),A(t), leaves tile t+1's 6 in flight — never drains to 0.
#define STEP(CBUF, SBUF, BC, BN2) do { \
    asm volatile("s_waitcnt vmcnt(6)" ::: "memory"); \
    __builtin_amdgcn_s_barrier(); \
    LDB(BN2); \
    AGLD(SBUF); \
    COMPUTE(CBUF, BC); \
} while (0)

    // Prologue: tiles 0 and 1 in flight (6 VMEM ops each).
    LDB(b0f); AGLD(0);
    LDB(b1f); AGLD(ABUF);

    // Main loop: tiles 0..35 (12 x 3, fully static buffer/set refs).
    for (int t = 0; t < 36; t += 3) {
        STEP(0,        2 * ABUF, b0f, b2f);
        STEP(ABUF,     0,        b1f, b0f);
        STEP(2 * ABUF, ABUF,     b2f, b1f);
    }
    // t=36: stages tile 38 (last), computes tile 36.
    STEP(0, 2 * ABUF, b0f, b2f);

    // t=37: tile 38's 6 VMEM ops still in flight.
    asm volatile("s_waitcnt vmcnt(6)" ::: "memory");
    __builtin_amdgcn_s_barrier();
    COMPUTE(ABUF, b1f);
    // t=38: drain.
    asm volatile("s_waitcnt vmcnt(0)" ::: "memory");
    __builtin_amdgcn_s_barrier();
    COMPUTE(2 * ABUF, b2f);

#undef STEP
#undef COMPUTE
#undef AGLD
#undef LDB

    // Epilogue (verified R5 mapping, dtype-independent): col = lane&15,
    // row = (lane>>4)*4 + reg. cross = acc/127^2; C = (2*cross - xs - ms)/500.
    const int fr   = lane & 15;
    const int row0 = bm * BM + wm * 64 + (lane >> 4) * 4;
    const int col0 = bn * BN + wn * 64 + fr;
    float ms[4];
    #pragma unroll
    for (int ni = 0; ni < 4; ++ni) ms[ni] = msq[col0 + ni * 16];
    #pragma unroll
    for (int mi = 0; mi < 4; ++mi) {
        #pragma unroll
        for (int r = 0; r < 4; ++r) {
            const int row = row0 + mi * 16 + r;
            const float xs = xsq[row];
            #pragma unroll
            for (int ni = 0; ni < 4; ++ni) {
                const float cr2 = (float)acc[mi][ni][r] * (2.0f / QSCALE2);
                const float v = (cr2 - xs - ms[ni]) * (1.0f / 500.0f);
                C[(size_t)row * N + col0 + ni * 16] = v;
            }
        }
    }
}

// ---------------------------------------------------------------------------
extern "C" void kernel_launch(void* const* d_in, const int* in_sizes, int n_in,
                              void* d_out, int out_size, void* d_ws, size_t ws_size,
                              hipStream_t stream) {
    const float* X  = (const float*)d_in[0];  // [4096, 2496]
    const float* Mx = (const float*)d_in[1];  // [2048, 2496]
    float* out = (float*)d_out;               // [4096, 2048]

    // Workspace layout (~15.4 MB): Xq u8 | Mq u8 | xsq f32 | msq f32
    unsigned char* Xq = (unsigned char*)d_ws;
    unsigned char* Mq = Xq + (size_t)B_DIM * D_DIM;
    float* xsq = (float*)(Mq + (size_t)S_DIM * D_DIM);
    float* msq = xsq + B_DIM;

    prep_kernel<<<(B_DIM + S_DIM) / 4, 256, 0, stream>>>(X, Mx, Xq, Mq, xsq, msq);

    dim3 grid(512);  // 32 bm x 16 bn via XCD-resident mapping, 2 blocks/CU
    gemm_kernel<<<grid, 256, 0, stream>>>(Xq, Mq, xsq, msq, out);
}

// Round 5
// 127.637 us; speedup vs baseline: 1.0442x; 1.0442x over previous
//
#include <hip/hip_runtime.h>
#include <cstdint>
#include <cstddef>

// Problem constants
#define B_DIM 4096   // batch (GEMM M)
#define S_DIM 2048   // states (GEMM N)
#define D_DIM 2496   // feature dim (GEMM K) = 13 * 192
#define QSCALE 127.0f
#define QSCALE2 16129.0f   // 127^2

// R11: REVERT to the best-measured kernel (round-0 baseline, 127.68us).
// R7 (2-phase dbuf), R8 (conflict-free slot-major + counted vmcnt), R9
// (B-resident XCD mapping), R10 (B LDS-bypass) each attacked a different
// candidate mechanism — drain, bank conflicts, L2 drift, LDS port — and all
// landed 127.7-133.3, i.e. neutral-or-worse vs this baseline. The end-to-end
// window is dominated by fixed terms (2x ~42us 256-MiB harness poison fills
// at 80% HBM = the entire rocprof top-5 in every round, prep at its 12.1us
// BW floor, gemm ~25-30us that four independent structural rewrites could
// not reduce). Keeping the best point measured.
#define BM 128
#define BN 128
#define BK 192
#define KITERS (D_DIM / BK)   // 13

typedef __attribute__((ext_vector_type(4))) int int4v;

// ---------------------------------------------------------------------------
struct __attribute__((aligned(8))) uc8 { unsigned char c[8]; };

// Prep, wave-per-row: quantize one row to u8 in [0,127] (RTN) and compute the
// EXACT fp32 squared norm of the original floats via shuffle reduce.
__global__ __launch_bounds__(256) void prep_kernel(
    const float* __restrict__ X, const float* __restrict__ Mx,
    unsigned char* __restrict__ Xq, unsigned char* __restrict__ Mq,
    float* __restrict__ xsq, float* __restrict__ msq)
{
    const int lane = threadIdx.x & 63;
    const int row  = blockIdx.x * 4 + (threadIdx.x >> 6);

    const float* src; unsigned char* dst; float* sq;
    if (row < B_DIM) {
        src = X + (size_t)row * D_DIM; dst = Xq + (size_t)row * D_DIM; sq = xsq + row;
    } else {
        const int r = row - B_DIM;
        src = Mx + (size_t)r * D_DIM; dst = Mq + (size_t)r * D_DIM; sq = msq + r;
    }

    const float4* s4 = (const float4*)src;
    uc8* d8 = (uc8*)dst;
    float acc = 0.f;
    for (int i = lane; i < D_DIM / 8; i += 64) {
        float4 a = s4[2 * i], b = s4[2 * i + 1];
        acc += a.x * a.x + a.y * a.y + a.z * a.z + a.w * a.w;
        acc += b.x * b.x + b.y * b.y + b.z * b.z + b.w * b.w;
        uc8 q;
        q.c[0] = (unsigned char)__float2int_rn(a.x * QSCALE);
        q.c[1] = (unsigned char)__float2int_rn(a.y * QSCALE);
        q.c[2] = (unsigned char)__float2int_rn(a.z * QSCALE);
        q.c[3] = (unsigned char)__float2int_rn(a.w * QSCALE);
        q.c[4] = (unsigned char)__float2int_rn(b.x * QSCALE);
        q.c[5] = (unsigned char)__float2int_rn(b.y * QSCALE);
        q.c[6] = (unsigned char)__float2int_rn(b.z * QSCALE);
        q.c[7] = (unsigned char)__float2int_rn(b.w * QSCALE);
        d8[i] = q;
    }
    #pragma unroll
    for (int off = 32; off > 0; off >>= 1)
        acc += __shfl_down(acc, off, 64);
    if (lane == 0) *sq = acc;
}

// ---------------------------------------------------------------------------
// global -> LDS direct (async) load, 16 B per lane; dest = wave-uniform base +
// lane*16, i.e. one issue fills 1024 contiguous LDS bytes.
__device__ __forceinline__ void gld_lds16(const unsigned char* g, unsigned char* l) {
    __builtin_amdgcn_global_load_lds(
        (const __attribute__((address_space(1))) unsigned int*)g,
        (__attribute__((address_space(3))) unsigned int*)l,
        16, 0, 0);
}

// ---------------------------------------------------------------------------
// C[row,col] = (2*cross - xsq[row] - msq[col]) / 500, cross = acc_i32/127^2.
// A: [4096, 2496] u8 row-major; Bt: [2048, 2496] u8 row-major (NT GEMM).
//
// LDS layout (chunked so gld_lds16's contiguous 1024-B landing zone works
// with BK=192): the tile is stored as chunks of 16 rows x 64 k-bytes.
// Chunk index = rowblock*3 + kseg (rowblock = row>>4, kseg = 0..2);
// within chunk: row_local*64 + byte. Fragment reads within a chunk have
// exactly R5's row*64 stride -> same (known-good) bank-conflict profile.
__global__ __launch_bounds__(256) void gemm_kernel(
    const unsigned char* __restrict__ A,
    const unsigned char* __restrict__ Bt,
    const float* __restrict__ xsq, const float* __restrict__ msq,
    float* __restrict__ C)
{
    constexpr int N = S_DIM;
    constexpr int K = D_DIM;   // bytes per row

    __shared__ __align__(16) unsigned char As[BM * BK];  // 24 KB (24 chunks)
    __shared__ __align__(16) unsigned char Bs[BN * BK];  // 24 KB

    const int tid  = threadIdx.x;
    const int lane = tid & 63;
    const int wave = tid >> 6;       // 4 waves
    const int wm = wave >> 1;        // wave row (0..1) -> 64 rows
    const int wn = wave & 1;         // wave col (0..1) -> 64 cols
    const int bm = blockIdx.y;
    const int bn = blockIdx.x;

    // Staging: each wave stages its 32 rows (2 rowblocks) x 3 ksegs for both
    // A and B = 12 gld_lds16 per iter. Lane i -> row_local (i>>2), byte
    // (i&3)*16 within the 16x64 chunk.
    const int srow  = lane >> 2;
    const int sbyte = (lane & 3) * 16;
    const unsigned char* gA = A  + (size_t)(bm * BM + wave * 32 + srow) * K + sbyte;
    const unsigned char* gB = Bt + (size_t)(bn * BN + wave * 32 + srow) * K + sbyte;
    // This wave's first chunk (rowblock 2*wave, kseg 0); 6 consecutive chunks.
    unsigned char* lA = &As[(wave * 2 * 3) * 1024];
    unsigned char* lB = &Bs[(wave * 2 * 3) * 1024];

    int4v acc[4][4] = {};

    // i8 16x16x64 A/B fragment (verified R5): m (or n) = lane&15,
    // k = (lane>>4)*16 + j. One ds_read_b128 per fragment.
    const int ko = (lane >> 4) * 16;  // byte offset within 64-B k-window
    const int fr = lane & 15;

    for (int t = 0; t < KITERS; ++t) {   // 13 iterations
        __syncthreads();   // previous tile fully consumed
        #pragma unroll
        for (int c = 0; c < 3; ++c) {
            gld_lds16(gA + c * 64,                  lA + (c    ) * 1024);
            gld_lds16(gA + (size_t)16 * K + c * 64, lA + (c + 3) * 1024);
            gld_lds16(gB + c * 64,                  lB + (c    ) * 1024);
            gld_lds16(gB + (size_t)16 * K + c * 64, lB + (c + 3) * 1024);
        }
        gA += BK; gB += BK;
        __syncthreads();   // drains vmcnt(0) — 13 drains total vs R5's 39

        #pragma unroll
        for (int s = 0; s < 3; ++s) {    // three 64-byte k-steps
            int4v af[4], bfr[4];
            #pragma unroll
            for (int i = 0; i < 4; ++i) {
                // row m = wm*64 + i*16 + fr -> rowblock wm*4+i, row_local fr
                af[i]  = *(const int4v*)&As[((wm * 4 + i) * 3 + s) * 1024 + fr * 64 + ko];
                bfr[i] = *(const int4v*)&Bs[((wn * 4 + i) * 3 + s) * 1024 + fr * 64 + ko];
            }
            #pragma unroll
            for (int mi = 0; mi < 4; ++mi)
                #pragma unroll
                for (int ni = 0; ni < 4; ++ni)
                    acc[mi][ni] = __builtin_amdgcn_mfma_i32_16x16x64_i8(
                        af[mi], bfr[ni], acc[mi][ni], 0, 0, 0);
        }
    }

    // Epilogue. C/D layout dtype-independent (m121-m128): col = lane&15,
    // row = (lane>>4)*4 + reg. cross = acc/127^2 in fp32.
    const int row0 = bm * BM + wm * 64 + (lane >> 4) * 4;
    const int col0 = bn * BN + wn * 64 + fr;
    float ms[4];
    #pragma unroll
    for (int ni = 0; ni < 4; ++ni) ms[ni] = msq[col0 + ni * 16];
    #pragma unroll
    for (int mi = 0; mi < 4; ++mi) {
        #pragma unroll
        for (int r = 0; r < 4; ++r) {
            const int row = row0 + mi * 16 + r;
            const float xs = xsq[row];
            #pragma unroll
            for (int ni = 0; ni < 4; ++ni) {
                const float cr2 = (float)acc[mi][ni][r] * (2.0f / QSCALE2);
                const float v = (cr2 - xs - ms[ni]) * (1.0f / 500.0f);
                C[(size_t)row * N + col0 + ni * 16] = v;
            }
        }
    }
}

// ---------------------------------------------------------------------------
extern "C" void kernel_launch(void* const* d_in, const int* in_sizes, int n_in,
                              void* d_out, int out_size, void* d_ws, size_t ws_size,
                              hipStream_t stream) {
    const float* X  = (const float*)d_in[0];  // [4096, 2496]
    const float* Mx = (const float*)d_in[1];  // [2048, 2496]
    float* out = (float*)d_out;               // [4096, 2048]

    // Workspace layout (~15.4 MB): Xq u8 | Mq u8 | xsq f32 | msq f32
    unsigned char* Xq = (unsigned char*)d_ws;
    unsigned char* Mq = Xq + (size_t)B_DIM * D_DIM;
    float* xsq = (float*)(Mq + (size_t)S_DIM * D_DIM);
    float* msq = xsq + B_DIM;

    prep_kernel<<<(B_DIM + S_DIM) / 4, 256, 0, stream>>>(X, Mx, Xq, Mq, xsq, msq);

    dim3 grid(S_DIM / BN, B_DIM / BM);  // (16, 32) = 512 blocks -> 2/CU
    gemm_kernel<<<grid, 256, 0, stream>>>(Xq, Mq, xsq, msq, out);
}